// Round 1
// baseline (232.593 us; speedup 1.0000x reference)
//
#include <hip/hip_runtime.h>
#include <math.h>

#define NEVENTS 16384
#define LHIST   2048
#define NCOMP   20

__global__ __launch_bounds__(64) void markov_kernel(
        const int*   __restrict__ src,
        const int*   __restrict__ dst,
        const float* __restrict__ t,
        const float* __restrict__ x_pad,
        const float* __restrict__ t_pad,
        const float* __restrict__ emb_src,
        const float* __restrict__ emb_dst,
        const float* __restrict__ alpha_p,
        const float* __restrict__ beta_p,
        float*       __restrict__ out) {
    int e = blockIdx.x * blockDim.x + threadIdx.x;
    if (e >= NEVENTS) return;

    const float alpha = alpha_p[0];
    const float beta  = beta_p[0];

    // ---- Poisson base rate: softplus(<emb_src[src], emb_dst[dst]>) ----
    const int s = src[e];
    const int d = dst[e];
    const float* es = emb_src + (size_t)s * NCOMP;
    const float* ed = emb_dst + (size_t)d * NCOMP;
    float dot = 0.0f;
    #pragma unroll
    for (int c = 0; c < NCOMP; ++c) dot += es[c] * ed[c];
    // numerically stable softplus = max(x,0) + log1p(exp(-|x|))
    float sp = fmaxf(dot, 0.0f) + log1pf(expf(-fabsf(dot)));

    // ---- last-prev-event selection: t_pad row is sorted ascending ----
    // count = # elements strictly < t[e]  (lower_bound)
    const float tq = t[e];
    const float* row = t_pad + (size_t)e * LHIST;
    int lo = 0, hi = LHIST;
    while (lo < hi) {
        int mid = (lo + hi) >> 1;
        if (row[mid] < tq) lo = mid + 1; else hi = mid;
    }
    const int count = lo;

    float incr = 0.0f;
    if (count > 0) {
        const int idx = count - 1;                 // last event with t_pad < t
        const float tl = row[idx];
        const float xv = x_pad[(size_t)e * LHIST + idx];
        // sigmoid((x - MEAN_FEAT)/VAR_FEAT), MEAN=0.5 VAR=0.25
        const float z  = (xv - 0.5f) * 4.0f;
        const float xs = 1.0f / (1.0f + expf(-z));
        incr = alpha * xs * expf(-beta * (tq - tl));
    }

    out[e] = sp + incr;
}

extern "C" void kernel_launch(void* const* d_in, const int* in_sizes, int n_in,
                              void* d_out, int out_size, void* d_ws, size_t ws_size,
                              hipStream_t stream) {
    const int*   src     = (const int*)  d_in[0];
    const int*   dst     = (const int*)  d_in[1];
    const float* t       = (const float*)d_in[2];
    const float* x_pad   = (const float*)d_in[3];
    const float* t_pad   = (const float*)d_in[4];
    const float* emb_src = (const float*)d_in[5];
    const float* emb_dst = (const float*)d_in[6];
    const float* alpha_p = (const float*)d_in[7];
    const float* beta_p  = (const float*)d_in[8];
    float* out = (float*)d_out;

    // 64 threads/block, 256 blocks -> one wave on each of the 256 CUs.
    dim3 block(64);
    dim3 grid(NEVENTS / 64);
    markov_kernel<<<grid, block, 0, stream>>>(src, dst, t, x_pad, t_pad,
                                              emb_src, emb_dst, alpha_p, beta_p, out);
}